// Round 8
// baseline (1052.048 us; speedup 1.0000x reference)
//
#include <hip/hip_runtime.h>
#include <hip/hip_bf16.h>
#include <hip/hip_fp16.h>
#include <hip/hip_cooperative_groups.h>

namespace cg = cooperative_groups;

#define N_NODES 50000
#define N_EDGES 800000
#define DD 96
#define NLAYER 4
#define N_GRAPHS 256
#define BN_EPS 1e-5f
#define SLABS 8
#define SFEAT 12     // halfs per slab row (24 B)
#define CSR_BLOCKS 784   // x64 nodes = 50176 >= N_NODES

// ---------------- workspace layout (units: 4-byte elements) ----------------
enum : size_t {
  O_CNT    = 0,                        // int[N_NODES] (counts, later fill cursors)
  O_STATS  = O_CNT + N_NODES,          // float[4*192]
  O_POOL   = O_STATS + 4 * 192,        // float[N_GRAPHS*96]
  O_GCNT   = O_POOL + N_GRAPHS * DD,   // int[N_GRAPHS]
  ZERO_END = O_GCNT + N_GRAPHS,
  O_ROWPTR = ZERO_END,                 // int[N_NODES+1]
  O_DIS    = O_ROWPTR + N_NODES + 1,   // float[N_NODES]
  O_BSUMS  = O_DIS + N_NODES,          // int[1024]
  O_EDGE   = (O_BSUMS + 1024 + 3) & ~size_t(3),      // uint[N_EDGES+8]
  O_HWH    = (O_EDGE + N_EDGES + 8 + 3) & ~size_t(3), // half[8][50000][12] = 9.6MB
  O_P      = O_HWH + (size_t)SLABS * N_NODES * SFEAT / 2,  // float[N*96] agg
  WS_ELEMS = O_P + (size_t)N_NODES * DD
};

__device__ __forceinline__ void atomAddF(float* p, float v) {
  unsafeAtomicAdd(p, v);  // native global fp32 atomic
}

__device__ __forceinline__ float2 h2f(unsigned int u) {
  __half2 h = *(__half2*)&u;
  return __half22float2(h);
}

// ---------------- fused CSR build (single cooperative kernel) ----------------
// Phases: zero -> count+gcount -> block scan(64)+dis -> global scan -> offsets
//         +cursor reset -> fill. All former memsets/7 kernels in one launch.
__global__ __launch_bounds__(256) void k_csr(const int* __restrict__ ei,
                                             const int* __restrict__ batch,
                                             float* __restrict__ ws) {
  cg::grid_group grid = cg::this_grid();
  int*   cnt    = (int*)(ws + O_CNT);
  int*   gcnt   = (int*)(ws + O_GCNT);
  int*   rowptr = (int*)(ws + O_ROWPTR);
  float* dis    = ws + O_DIS;
  int*   bsums  = (int*)(ws + O_BSUMS);
  unsigned int* edg = (unsigned int*)(ws + O_EDGE);

  const int tid = threadIdx.x;
  const int b = blockIdx.x;
  const int gt = b * 256 + tid;
  const int gsz = gridDim.x * 256;

  // P0: zero cnt/stats/pool/gcnt + edge pad
  for (size_t i = gt; i < ZERO_END; i += gsz) ws[i] = 0.f;
  if (gt < 8) edg[N_EDGES + gt] = 0;
  grid.sync();

  // P1: in-degree count + per-graph node count
  for (int e = gt; e < N_EDGES; e += gsz) atomicAdd(&cnt[ei[N_EDGES + e]], 1);
  for (int n = gt; n < N_NODES; n += gsz) atomicAdd(&gcnt[batch[n]], 1);
  grid.sync();

  // P2: per-block scan of 64 counts + dis
  __shared__ int sc[64];
  const int base = b * 64;
  const int n64 = base + tid;
  int c0 = 0;
  if (tid < 64) {
    c0 = (n64 < N_NODES) ? cnt[n64] : 0;
    sc[tid] = c0;
    if (n64 < N_NODES) dis[n64] = rsqrtf((float)(c0 + 1));  // +1 self loop
  }
  __syncthreads();
  for (int off = 1; off < 64; off <<= 1) {
    int add = (tid < 64 && tid >= off) ? sc[tid - off] : 0;
    __syncthreads();
    if (tid < 64) sc[tid] += add;
    __syncthreads();
  }
  if (tid < 64 && n64 < N_NODES) rowptr[n64] = sc[tid] - c0;  // local exclusive
  if (tid == 63) bsums[b] = sc[63];
  grid.sync();

  // P3: block 0 scans bsums[0..CSR_BLOCKS) exclusive
  if (b == 0) {
    __shared__ int sb[256];
    int vals[4], mysum = 0;
#pragma unroll
    for (int i = 0; i < 4; ++i) {
      int idx = tid * 4 + i;
      vals[i] = (idx < CSR_BLOCKS) ? bsums[idx] : 0;
      mysum += vals[i];
    }
    sb[tid] = mysum;
    __syncthreads();
    for (int off = 1; off < 256; off <<= 1) {
      int add = (tid >= off) ? sb[tid - off] : 0;
      __syncthreads();
      sb[tid] += add;
      __syncthreads();
    }
    int run = sb[tid] - mysum;
#pragma unroll
    for (int i = 0; i < 4; ++i) {
      int idx = tid * 4 + i;
      if (idx < 1024) bsums[idx] = run;
      run += vals[i];
    }
    if (tid == 255) rowptr[N_NODES] = run;
  }
  grid.sync();

  // P4: add block offsets; reset cursors
  if (tid < 64 && n64 < N_NODES) {
    rowptr[n64] += bsums[b];
    cnt[n64] = 0;
  }
  grid.sync();

  // P5: fill packed edges (src | half(weight)<<16)
  for (int e = gt; e < N_EDGES; e += gsz) {
    int s = ei[e];
    int d = ei[N_EDGES + e];
    int pos = rowptr[d] + atomicAdd(&cnt[d], 1);
    unsigned short wb = __half_as_ushort(__float2half_rn(dis[s] * dis[d]));
    edg[pos] = (unsigned int)s | ((unsigned int)wb << 16);
  }
}

// ---------------- GEMM: Y(fp16 slab-major) = act(X) @ W  (R5 proven) ----------
__global__ __launch_bounds__(192) void k_gemm(const float* __restrict__ X,
                                              const float* __restrict__ Wg,
                                              const float* __restrict__ stats,
                                              const float* __restrict__ gamma,
                                              const float* __restrict__ beta,
                                              __half* __restrict__ Y) {
  __shared__ float Ws[96 * 96];
  __shared__ float Hs[48][100];
  __shared__ float sA[96], sC[96];
  const int tid = threadIdx.x;
  const int fg = tid % 24;
  const int rg = tid / 24;
  const int row0 = blockIdx.x * 48;

  for (int i = tid; i < 96 * 24; i += 192)
    *(float4*)&Ws[i * 4] = *(const float4*)&Wg[i * 4];
  if (tid < 96) {
    if (stats) {
      float mu = stats[tid] * (1.f / N_NODES);
      float var = fmaxf(stats[96 + tid] * (1.f / N_NODES) - mu * mu, 0.f);
      float a = gamma[tid] * rsqrtf(var + BN_EPS);
      sA[tid] = a;
      sC[tid] = beta[tid] - mu * a;
    } else {
      sA[tid] = 1.f;
      sC[tid] = 0.f;
    }
  }
  __syncthreads();
  const bool bn = (stats != nullptr);
  for (int i = tid; i < 48 * 24; i += 192) {
    int r = i / 24, c4 = (i % 24) * 4;
    int gr = row0 + r;
    float4 v = (gr < N_NODES) ? *(const float4*)&X[(size_t)gr * 96 + c4]
                              : make_float4(0.f, 0.f, 0.f, 0.f);
    if (bn) {
      v.x = fmaxf(v.x * sA[c4] + sC[c4], 0.f);
      v.y = fmaxf(v.y * sA[c4 + 1] + sC[c4 + 1], 0.f);
      v.z = fmaxf(v.z * sA[c4 + 2] + sC[c4 + 2], 0.f);
      v.w = fmaxf(v.w * sA[c4 + 3] + sC[c4 + 3], 0.f);
    }
    *(float4*)&Hs[r][c4] = v;
  }
  __syncthreads();

  float4 acc[6];
#pragma unroll
  for (int j = 0; j < 6; ++j) acc[j] = make_float4(0.f, 0.f, 0.f, 0.f);
  const int f4 = fg * 4;
  for (int k4 = 0; k4 < 96; k4 += 4) {
    float4 w0 = *(const float4*)&Ws[(k4 + 0) * 96 + f4];
    float4 w1 = *(const float4*)&Ws[(k4 + 1) * 96 + f4];
    float4 w2 = *(const float4*)&Ws[(k4 + 2) * 96 + f4];
    float4 w3 = *(const float4*)&Ws[(k4 + 3) * 96 + f4];
#pragma unroll
    for (int j = 0; j < 6; ++j) {
      const float4 h = *(const float4*)&Hs[rg + j * 8][k4];
      acc[j].x += h.x * w0.x + h.y * w1.x + h.z * w2.x + h.w * w3.x;
      acc[j].y += h.x * w0.y + h.y * w1.y + h.z * w2.y + h.w * w3.y;
      acc[j].z += h.x * w0.z + h.y * w1.z + h.z * w2.z + h.w * w3.z;
      acc[j].w += h.x * w0.w + h.y * w1.w + h.z * w2.w + h.w * w3.w;
    }
  }
  // write fp16 slab-major: slab = fg/3, offset (fg%3)*4 halfs within 12-half row
  const int slab = fg / 3;
  const int off = (fg % 3) * 4;
#pragma unroll
  for (int j = 0; j < 6; ++j) {
    int r = row0 + rg + j * 8;
    if (r < N_NODES) {
      union { uint2 u; __half2 h[2]; } pk;
      pk.h[0] = __floats2half2_rn(acc[j].x, acc[j].y);
      pk.h[1] = __floats2half2_rn(acc[j].z, acc[j].w);
      *(uint2*)&Y[((size_t)slab * N_NODES + r) * SFEAT + off] = pk.u;
    }
  }
}

// ---------------- fused aggregation + BN-stats (R5 champion config) ----------
// block b: slab = b & 7 (slab 1.2MB -> L2-resident per XCD), chunk = b>>3.
// Group = 6 lanes per dst node; lane owns 2 fp16 channels. Wave = 10 nodes.
// 8-wide branchless edge unroll; cached scalar edge loads (line-shared in group).
__global__ __launch_bounds__(256) void k_gather(const __half* __restrict__ hwh,
                                                const int* __restrict__ rowptr,
                                                const unsigned int* __restrict__ edg,
                                                const float* __restrict__ dis,
                                                float* __restrict__ agg,
                                                float* __restrict__ stats) {
  __shared__ float sred[24];
  const int tid = threadIdx.x;
  const int slab = blockIdx.x & (SLABS - 1);
  const int chunk = blockIdx.x >> 3;
  const int wave = tid >> 6;
  const int lane = tid & 63;
  const int g = lane / 6;      // 0..10 (g==10 -> idle)
  const int ch = lane - g * 6; // channel pair index 0..5
  const int n = chunk * 40 + wave * 10 + g;
  const bool valid = (g < 10) && (n < N_NODES);
  const int nc = valid ? n : 0;

  const unsigned int* slabU =
      (const unsigned int*)(hwh) + (size_t)slab * N_NODES * (SFEAT / 2);

  if (tid < 24) sred[tid] = 0.f;

  const int js = valid ? rowptr[nc] : 0;
  const int je = valid ? rowptr[nc + 1] : 0;

  float a0 = 0.f, a1 = 0.f;
  if (valid) {
    float dn = dis[nc];
    float s2 = dn * dn;  // self-loop weight
    float2 f = h2f(slabU[nc * 6 + ch]);
    a0 = f.x * s2;
    a1 = f.y * s2;
  }

  for (int j = js; j < je; j += 8) {
    unsigned int ew[8];
    unsigned int rv[8];
#pragma unroll
    for (int k = 0; k < 8; ++k) {
      int jk = j + k;
      int jc = jk < je ? jk : (je - 1);  // clamp to hot line
      ew[k] = edg[jc];
    }
#pragma unroll
    for (int k = 0; k < 8; ++k)
      rv[k] = slabU[(int)(ew[k] & 0xFFFFu) * 6 + ch];
#pragma unroll
    for (int k = 0; k < 8; ++k) {
      float w = (j + k < je)
                    ? __half2float(__ushort_as_half((unsigned short)(ew[k] >> 16)))
                    : 0.f;
      float2 f = h2f(rv[k]);
      a0 = fmaf(w, f.x, a0);
      a1 = fmaf(w, f.y, a1);
    }
  }

  if (valid) {
    *(float2*)&agg[(size_t)n * DD + slab * SFEAT + ch * 2] = make_float2(a0, a1);
  }

  __syncthreads();
  if (valid) {
    atomicAdd(&sred[ch * 2], a0);          // LDS ds_add_f32
    atomicAdd(&sred[ch * 2 + 1], a1);
    atomicAdd(&sred[12 + ch * 2], a0 * a0);
    atomicAdd(&sred[13 + ch * 2], a1 * a1);
  }
  __syncthreads();
  if (tid < 24) {
    int c = (tid < 12) ? (slab * SFEAT + tid) : (96 + slab * SFEAT + tid - 12);
    atomAddF(&stats[c], sred[tid]);
  }
}

// ---------------- pooling + output (single cooperative kernel) ----------------
__global__ __launch_bounds__(192) void k_poolout(const float* __restrict__ h,
                                                 const float* __restrict__ stats,
                                                 const float* __restrict__ gamma,
                                                 const float* __restrict__ beta,
                                                 const int* __restrict__ batch,
                                                 const int* __restrict__ gcnt,
                                                 float* __restrict__ pool,
                                                 float* __restrict__ out) {
  cg::grid_group gr = cg::this_grid();
  __shared__ float sA[96], sC[96];
  const int tid = threadIdx.x;
  if (tid < 96) {
    float mu = stats[tid] * (1.f / N_NODES);
    float var = fmaxf(stats[96 + tid] * (1.f / N_NODES) - mu * mu, 0.f);
    float a = gamma[tid] * rsqrtf(var + BN_EPS);
    sA[tid] = a;
    sC[tid] = beta[tid] - mu * a;
  }
  __syncthreads();
  const int chain = blockIdx.x * 8 + tid / 24;
  const int q4 = (tid % 24) * 4;
  const int n0 = chain * 32;
  if (n0 < N_NODES) {  // no early return: all threads must reach grid sync
    int n1 = min(n0 + 32, N_NODES);
    float A0 = sA[q4], A1 = sA[q4 + 1], A2 = sA[q4 + 2], A3 = sA[q4 + 3];
    float C0 = sC[q4], C1 = sC[q4 + 1], C2 = sC[q4 + 2], C3 = sC[q4 + 3];
    int cur = batch[n0];
    float4 acc = make_float4(0.f, 0.f, 0.f, 0.f);
    for (int n = n0; n < n1; ++n) {
      int gg = batch[n];
      if (gg != cur) {
        float* p = &pool[cur * 96 + q4];
        atomAddF(p, acc.x); atomAddF(p + 1, acc.y);
        atomAddF(p + 2, acc.z); atomAddF(p + 3, acc.w);
        acc = make_float4(0.f, 0.f, 0.f, 0.f);
        cur = gg;
      }
      const float4 v = *(const float4*)&h[(size_t)n * 96 + q4];
      acc.x += fmaxf(v.x * A0 + C0, 0.f);
      acc.y += fmaxf(v.y * A1 + C1, 0.f);
      acc.z += fmaxf(v.z * A2 + C2, 0.f);
      acc.w += fmaxf(v.w * A3 + C3, 0.f);
    }
    float* p = &pool[cur * 96 + q4];
    atomAddF(p, acc.x); atomAddF(p + 1, acc.y);
    atomAddF(p + 2, acc.z); atomAddF(p + 3, acc.w);
  }
  gr.sync();
  const int gt = blockIdx.x * 192 + tid;
  const int gsz = gridDim.x * 192;
  for (int t = gt; t < N_GRAPHS * 96; t += gsz) {
    int c = gcnt[t / 96];
    if (c < 1) c = 1;
    out[t] = pool[t] / (float)c;
  }
}

extern "C" void kernel_launch(void* const* d_in, const int* in_sizes, int n_in,
                              void* d_out, int out_size, void* d_ws, size_t ws_size,
                              hipStream_t stream) {
  const float* x     = (const float*)d_in[0];
  const int*   ei    = (const int*)d_in[1];   // [2, E]: src row then dst row
  const int*   batch = (const int*)d_in[2];
  const float* W     = (const float*)d_in[3]; // [4,96,96]
  // d_in[4] = b : cancels exactly through BatchNorm, unused
  const float* gamma = (const float*)d_in[5]; // [4,96]
  const float* beta  = (const float*)d_in[6];
  float* out = (float*)d_out;

  float* ws = (float*)d_ws;
  float* stats  = ws + O_STATS;
  float* pool   = ws + O_POOL;
  int*   gcnt   = (int*)(ws + O_GCNT);
  int*   rowptr = (int*)(ws + O_ROWPTR);
  float* dis    = ws + O_DIS;
  unsigned int* edg = (unsigned int*)(ws + O_EDGE);
  __half* hwh   = (__half*)(ws + O_HWH);
  float* P      = ws + O_P;  // agg (fp32)

  // ---- 1 launch: full CSR build (replaces 2 memsets + 7 kernels) ----
  {
    void* args[] = {(void*)&ei, (void*)&batch, (void*)&ws};
    hipLaunchCooperativeKernel((const void*)k_csr, dim3(CSR_BLOCKS), dim3(256),
                               args, 0, stream);
  }

  const int gemmb = (N_NODES + 47) / 48;              // 1042
  const int gatherb = SLABS * ((N_NODES + 39) / 40);  // 10000

  const float* hin = x;
  for (int l = 0; l < NLAYER; ++l) {
    const float* st = (l == 0) ? nullptr : (stats + (l - 1) * 192);
    const float* ga = (l == 0) ? nullptr : (gamma + (l - 1) * 96);
    const float* be = (l == 0) ? nullptr : (beta + (l - 1) * 96);
    k_gemm<<<gemmb, 192, 0, stream>>>(hin, W + l * 96 * 96, st, ga, be, hwh);
    k_gather<<<gatherb, 256, 0, stream>>>(hwh, rowptr, edg, dis, P, stats + l * 192);
    hin = P;
  }

  // ---- 1 launch: pool + out ----
  {
    const float* h = P;
    const float* st = stats + 3 * 192;
    const float* ga = gamma + 3 * 96;
    const float* be = beta + 3 * 96;
    const int* bt = batch;
    const int* gc = gcnt;
    float* pl = pool;
    float* ot = out;
    void* args[] = {(void*)&h, (void*)&st, (void*)&ga, (void*)&be,
                    (void*)&bt, (void*)&gc, (void*)&pl, (void*)&ot};
    hipLaunchCooperativeKernel((const void*)k_poolout, dim3(196), dim3(192),
                               args, 0, stream);
  }
}

// Round 9
// 651.030 us; speedup vs baseline: 1.6160x; 1.6160x over previous
//
#include <hip/hip_runtime.h>
#include <hip/hip_bf16.h>
#include <hip/hip_fp16.h>

#define N_NODES 50000
#define N_EDGES 800000
#define DD 96
#define NLAYER 4
#define N_GRAPHS 256
#define BN_EPS 1e-5f
#define SLABS 8
#define SFEAT 12  // halfs per slab row (24 B); SLABS*SFEAT = 96

// ---------------- workspace layout (units: 4-byte elements) ----------------
enum : size_t {
  O_CNT    = 0,                        // int[N_NODES] (counts, later fill cursors)
  O_STATS  = O_CNT + N_NODES,          // float[4*192]  (sum, sumsq per layer)
  O_POOL   = O_STATS + 4 * 192,        // float[N_GRAPHS*96]
  O_GCNT   = O_POOL + N_GRAPHS * DD,   // int[N_GRAPHS]
  ZERO_END = O_GCNT + N_GRAPHS,
  O_ROWPTR = ZERO_END,                 // int[N_NODES+1]
  O_DIS    = O_ROWPTR + N_NODES + 1,   // float[N_NODES]
  O_BSUMS  = O_DIS + N_NODES,          // int[256]
  O_EDGE   = (O_BSUMS + 256 + 3) & ~size_t(3),       // uint[N_EDGES+8]
  O_HWH    = (O_EDGE + N_EDGES + 8 + 3) & ~size_t(3), // half[8][50000][12] = 9.6MB
  O_P      = O_HWH + (size_t)SLABS * N_NODES * SFEAT / 2,  // float[N*96] agg
  WS_ELEMS = O_P + (size_t)N_NODES * DD
};

__device__ __forceinline__ void atomAddF(float* p, float v) {
  unsafeAtomicAdd(p, v);  // native global fp32 atomic
}

__device__ __forceinline__ float2 h2f(unsigned int u) {
  __half2 h = *(__half2*)&u;
  return __half22float2(h);
}

// ---------------- CSR build ----------------
// in-degree count + per-graph node count (same grid covers both ranges)
__global__ void k_count(const int* __restrict__ dst, const int* __restrict__ batch,
                        int* __restrict__ cnt, int* __restrict__ gcnt) {
  int e = blockIdx.x * blockDim.x + threadIdx.x;
  if (e < N_EDGES) atomicAdd(&cnt[dst[e]], 1);
  if (e < N_NODES) atomicAdd(&gcnt[batch[e]], 1);
}

// per-block reduction of 256 counts + dis = rsqrt(deg+1)
__global__ void k_partials(const int* __restrict__ cnt, int* __restrict__ bsums,
                           float* __restrict__ dis) {
  __shared__ int s[256];
  int i = blockIdx.x * 256 + threadIdx.x;
  int c = (i < N_NODES) ? cnt[i] : 0;
  s[threadIdx.x] = c;
  if (i < N_NODES) dis[i] = rsqrtf((float)(c + 1));  // +1 self loop
  __syncthreads();
  for (int off = 128; off > 0; off >>= 1) {
    if (threadIdx.x < off) s[threadIdx.x] += s[threadIdx.x + off];
    __syncthreads();
  }
  if (threadIdx.x == 0) bsums[blockIdx.x] = s[0];
}

// parallel exclusive scan of bsums[0..nb) in one 256-thread block
__global__ void k_scan_bsums(int* __restrict__ bsums, int nb, int* __restrict__ rowptr) {
  __shared__ int s[256];
  int tid = threadIdx.x;
  int v = (tid < nb) ? bsums[tid] : 0;
  s[tid] = v;
  __syncthreads();
  for (int off = 1; off < 256; off <<= 1) {
    int add = (tid >= off) ? s[tid - off] : 0;
    __syncthreads();
    s[tid] += add;
    __syncthreads();
  }
  if (tid < nb) bsums[tid] = s[tid] - v;  // exclusive
  if (tid == 255) rowptr[N_NODES] = s[255];
}

// block-local exclusive scan + global offset; also resets cnt as fill cursor
__global__ void k_scan_write(int* __restrict__ cnt, const int* __restrict__ bsums,
                             int* __restrict__ rowptr) {
  __shared__ int s[256];
  int i = blockIdx.x * 256 + threadIdx.x;
  int v = (i < N_NODES) ? cnt[i] : 0;
  s[threadIdx.x] = v;
  __syncthreads();
  for (int off = 1; off < 256; off <<= 1) {
    int x = 0;
    if (threadIdx.x >= off) x = s[threadIdx.x - off];
    __syncthreads();
    s[threadIdx.x] += x;
    __syncthreads();
  }
  if (i < N_NODES) {
    rowptr[i] = bsums[blockIdx.x] + s[threadIdx.x] - v;  // exclusive
    cnt[i] = 0;  // reset as fill cursor (replaces memset)
  }
}

__global__ void k_fill(const int* __restrict__ ei, const int* __restrict__ rowptr,
                       int* __restrict__ cursor, const float* __restrict__ dis,
                       unsigned int* __restrict__ edg) {
  int e = blockIdx.x * blockDim.x + threadIdx.x;
  if (blockIdx.x == 0 && threadIdx.x < 8) edg[N_EDGES + threadIdx.x] = 0;  // pad
  if (e >= N_EDGES) return;
  int s = ei[e];            // src (< 65536)
  int d = ei[N_EDGES + e];  // dst
  int pos = rowptr[d] + atomicAdd(&cursor[d], 1);
  unsigned short wb = __half_as_ushort(__float2half_rn(dis[s] * dis[d]));
  edg[pos] = (unsigned int)s | ((unsigned int)wb << 16);
}

// ---------------- GEMM: Y(fp16 slab-major) = act(X) @ W  (R5 proven) ----------
__global__ __launch_bounds__(192) void k_gemm(const float* __restrict__ X,
                                              const float* __restrict__ Wg,
                                              const float* __restrict__ stats,
                                              const float* __restrict__ gamma,
                                              const float* __restrict__ beta,
                                              __half* __restrict__ Y) {
  __shared__ float Ws[96 * 96];
  __shared__ float Hs[48][100];
  __shared__ float sA[96], sC[96];
  const int tid = threadIdx.x;
  const int fg = tid % 24;
  const int rg = tid / 24;
  const int row0 = blockIdx.x * 48;

  for (int i = tid; i < 96 * 24; i += 192)
    *(float4*)&Ws[i * 4] = *(const float4*)&Wg[i * 4];
  if (tid < 96) {
    if (stats) {
      float mu = stats[tid] * (1.f / N_NODES);
      float var = fmaxf(stats[96 + tid] * (1.f / N_NODES) - mu * mu, 0.f);
      float a = gamma[tid] * rsqrtf(var + BN_EPS);
      sA[tid] = a;
      sC[tid] = beta[tid] - mu * a;
    } else {
      sA[tid] = 1.f;
      sC[tid] = 0.f;
    }
  }
  __syncthreads();
  const bool bn = (stats != nullptr);
  for (int i = tid; i < 48 * 24; i += 192) {
    int r = i / 24, c4 = (i % 24) * 4;
    int gr = row0 + r;
    float4 v = (gr < N_NODES) ? *(const float4*)&X[(size_t)gr * 96 + c4]
                              : make_float4(0.f, 0.f, 0.f, 0.f);
    if (bn) {
      v.x = fmaxf(v.x * sA[c4] + sC[c4], 0.f);
      v.y = fmaxf(v.y * sA[c4 + 1] + sC[c4 + 1], 0.f);
      v.z = fmaxf(v.z * sA[c4 + 2] + sC[c4 + 2], 0.f);
      v.w = fmaxf(v.w * sA[c4 + 3] + sC[c4 + 3], 0.f);
    }
    *(float4*)&Hs[r][c4] = v;
  }
  __syncthreads();

  float4 acc[6];
#pragma unroll
  for (int j = 0; j < 6; ++j) acc[j] = make_float4(0.f, 0.f, 0.f, 0.f);
  const int f4 = fg * 4;
  for (int k4 = 0; k4 < 96; k4 += 4) {
    float4 w0 = *(const float4*)&Ws[(k4 + 0) * 96 + f4];
    float4 w1 = *(const float4*)&Ws[(k4 + 1) * 96 + f4];
    float4 w2 = *(const float4*)&Ws[(k4 + 2) * 96 + f4];
    float4 w3 = *(const float4*)&Ws[(k4 + 3) * 96 + f4];
#pragma unroll
    for (int j = 0; j < 6; ++j) {
      const float4 h = *(const float4*)&Hs[rg + j * 8][k4];
      acc[j].x += h.x * w0.x + h.y * w1.x + h.z * w2.x + h.w * w3.x;
      acc[j].y += h.x * w0.y + h.y * w1.y + h.z * w2.y + h.w * w3.y;
      acc[j].z += h.x * w0.z + h.y * w1.z + h.z * w2.z + h.w * w3.z;
      acc[j].w += h.x * w0.w + h.y * w1.w + h.z * w2.w + h.w * w3.w;
    }
  }
  // write fp16 slab-major: slab = fg/3, offset (fg%3)*4 halfs within 12-half row
  const int slab = fg / 3;
  const int off = (fg % 3) * 4;
#pragma unroll
  for (int j = 0; j < 6; ++j) {
    int r = row0 + rg + j * 8;
    if (r < N_NODES) {
      union { uint2 u; __half2 h[2]; } pk;
      pk.h[0] = __floats2half2_rn(acc[j].x, acc[j].y);
      pk.h[1] = __floats2half2_rn(acc[j].z, acc[j].w);
      *(uint2*)&Y[((size_t)slab * N_NODES + r) * SFEAT + off] = pk.u;
    }
  }
}

// ---------------- fused aggregation + BN-stats (R5 champion config) ----------
// block b: slab = b & 7 (slab 1.2MB -> L2-resident per XCD), chunk = b>>3.
// Group = 6 lanes per dst node; lane owns 2 fp16 channels. Wave = 10 nodes.
// 8-wide branchless edge unroll; cached scalar edge loads (line-shared in group).
__global__ __launch_bounds__(256) void k_gather(const __half* __restrict__ hwh,
                                                const int* __restrict__ rowptr,
                                                const unsigned int* __restrict__ edg,
                                                const float* __restrict__ dis,
                                                float* __restrict__ agg,
                                                float* __restrict__ stats) {
  __shared__ float sred[24];
  const int tid = threadIdx.x;
  const int slab = blockIdx.x & (SLABS - 1);
  const int chunk = blockIdx.x >> 3;
  const int wave = tid >> 6;
  const int lane = tid & 63;
  const int g = lane / 6;      // 0..10 (g==10 -> idle)
  const int ch = lane - g * 6; // channel pair index 0..5
  const int n = chunk * 40 + wave * 10 + g;
  const bool valid = (g < 10) && (n < N_NODES);
  const int nc = valid ? n : 0;

  const unsigned int* slabU =
      (const unsigned int*)(hwh) + (size_t)slab * N_NODES * (SFEAT / 2);

  if (tid < 24) sred[tid] = 0.f;

  const int js = valid ? rowptr[nc] : 0;
  const int je = valid ? rowptr[nc + 1] : 0;

  float a0 = 0.f, a1 = 0.f;
  if (valid) {
    float dn = dis[nc];
    float s2 = dn * dn;  // self-loop weight
    float2 f = h2f(slabU[nc * 6 + ch]);
    a0 = f.x * s2;
    a1 = f.y * s2;
  }

  for (int j = js; j < je; j += 8) {
    unsigned int ew[8];
    unsigned int rv[8];
#pragma unroll
    for (int k = 0; k < 8; ++k) {
      int jk = j + k;
      int jc = jk < je ? jk : (je - 1);  // clamp to hot line
      ew[k] = edg[jc];
    }
#pragma unroll
    for (int k = 0; k < 8; ++k)
      rv[k] = slabU[(int)(ew[k] & 0xFFFFu) * 6 + ch];
#pragma unroll
    for (int k = 0; k < 8; ++k) {
      float w = (j + k < je)
                    ? __half2float(__ushort_as_half((unsigned short)(ew[k] >> 16)))
                    : 0.f;
      float2 f = h2f(rv[k]);
      a0 = fmaf(w, f.x, a0);
      a1 = fmaf(w, f.y, a1);
    }
  }

  if (valid) {
    *(float2*)&agg[(size_t)n * DD + slab * SFEAT + ch * 2] = make_float2(a0, a1);
  }

  __syncthreads();
  if (valid) {
    atomicAdd(&sred[ch * 2], a0);          // LDS ds_add_f32
    atomicAdd(&sred[ch * 2 + 1], a1);
    atomicAdd(&sred[12 + ch * 2], a0 * a0);
    atomicAdd(&sred[13 + ch * 2], a1 * a1);
  }
  __syncthreads();
  if (tid < 24) {
    int c = (tid < 12) ? (slab * SFEAT + tid) : (96 + slab * SFEAT + tid - 12);
    atomAddF(&stats[c], sred[tid]);
  }
}

// ---------------- pooling: final BN+ReLU + segment-sum over sorted batch ------
__global__ __launch_bounds__(192) void k_pool(const float* __restrict__ h,
                                              const float* __restrict__ stats,
                                              const float* __restrict__ gamma,
                                              const float* __restrict__ beta,
                                              const int* __restrict__ batch,
                                              float* __restrict__ pool) {
  __shared__ float sA[96], sC[96];
  const int tid = threadIdx.x;
  if (tid < 96) {
    float mu = stats[tid] * (1.f / N_NODES);
    float var = fmaxf(stats[96 + tid] * (1.f / N_NODES) - mu * mu, 0.f);
    float a = gamma[tid] * rsqrtf(var + BN_EPS);
    sA[tid] = a;
    sC[tid] = beta[tid] - mu * a;
  }
  __syncthreads();
  const int chain = blockIdx.x * 8 + tid / 24;
  const int q4 = (tid % 24) * 4;
  int n0 = chain * 32;
  if (n0 >= N_NODES) return;
  int n1 = min(n0 + 32, N_NODES);
  float A0 = sA[q4], A1 = sA[q4 + 1], A2 = sA[q4 + 2], A3 = sA[q4 + 3];
  float C0 = sC[q4], C1 = sC[q4 + 1], C2 = sC[q4 + 2], C3 = sC[q4 + 3];
  int cur = batch[n0];
  float4 acc = make_float4(0.f, 0.f, 0.f, 0.f);
  for (int n = n0; n < n1; ++n) {
    int g = batch[n];
    if (g != cur) {
      float* p = &pool[cur * 96 + q4];
      atomAddF(p, acc.x); atomAddF(p + 1, acc.y);
      atomAddF(p + 2, acc.z); atomAddF(p + 3, acc.w);
      acc = make_float4(0.f, 0.f, 0.f, 0.f);
      cur = g;
    }
    const float4 v = *(const float4*)&h[(size_t)n * 96 + q4];
    acc.x += fmaxf(v.x * A0 + C0, 0.f);
    acc.y += fmaxf(v.y * A1 + C1, 0.f);
    acc.z += fmaxf(v.z * A2 + C2, 0.f);
    acc.w += fmaxf(v.w * A3 + C3, 0.f);
  }
  float* p = &pool[cur * 96 + q4];
  atomAddF(p, acc.x); atomAddF(p + 1, acc.y);
  atomAddF(p + 2, acc.z); atomAddF(p + 3, acc.w);
}

__global__ void k_out(const float* __restrict__ pool, const int* __restrict__ gcnt,
                      float* __restrict__ out) {
  int t = blockIdx.x * blockDim.x + threadIdx.x;
  if (t >= N_GRAPHS * 96) return;
  int g = t / 96;
  int c = gcnt[g];
  if (c < 1) c = 1;
  out[t] = pool[t] / (float)c;
}

extern "C" void kernel_launch(void* const* d_in, const int* in_sizes, int n_in,
                              void* d_out, int out_size, void* d_ws, size_t ws_size,
                              hipStream_t stream) {
  const float* x     = (const float*)d_in[0];
  const int*   ei    = (const int*)d_in[1];   // [2, E]: src row then dst row
  const int*   batch = (const int*)d_in[2];
  const float* W     = (const float*)d_in[3]; // [4,96,96]
  // d_in[4] = b : cancels exactly through BatchNorm, unused
  const float* gamma = (const float*)d_in[5]; // [4,96]
  const float* beta  = (const float*)d_in[6];
  float* out = (float*)d_out;

  float* ws = (float*)d_ws;
  int*   cnt    = (int*)(ws + O_CNT);
  float* stats  = ws + O_STATS;
  float* pool   = ws + O_POOL;
  int*   gcnt   = (int*)(ws + O_GCNT);
  int*   rowptr = (int*)(ws + O_ROWPTR);
  float* dis    = ws + O_DIS;
  int*   bsums  = (int*)(ws + O_BSUMS);
  unsigned int* edg = (unsigned int*)(ws + O_EDGE);
  __half* hwh   = (__half*)(ws + O_HWH);
  float* P      = ws + O_P;  // agg (fp32)

  hipMemsetAsync(d_ws, 0, ZERO_END * sizeof(float), stream);

  const int eb = (N_EDGES + 255) / 256;
  const int nb = (N_NODES + 255) / 256;  // 196
  k_count<<<eb, 256, 0, stream>>>(ei + N_EDGES, batch, cnt, gcnt);
  k_partials<<<nb, 256, 0, stream>>>(cnt, bsums, dis);
  k_scan_bsums<<<1, 256, 0, stream>>>(bsums, nb, rowptr);
  k_scan_write<<<nb, 256, 0, stream>>>(cnt, bsums, rowptr);
  k_fill<<<eb, 256, 0, stream>>>(ei, rowptr, cnt, dis, edg);

  const int gemmb = (N_NODES + 47) / 48;              // 1042
  const int gatherb = SLABS * ((N_NODES + 39) / 40);  // 10000

  const float* hin = x;
  for (int l = 0; l < NLAYER; ++l) {
    const float* st = (l == 0) ? nullptr : (stats + (l - 1) * 192);
    const float* ga = (l == 0) ? nullptr : (gamma + (l - 1) * 96);
    const float* be = (l == 0) ? nullptr : (beta + (l - 1) * 96);
    k_gemm<<<gemmb, 192, 0, stream>>>(hin, W + l * 96 * 96, st, ga, be, hwh);
    k_gather<<<gatherb, 256, 0, stream>>>(hwh, rowptr, edg, dis, P, stats + l * 192);
    hin = P;
  }

  const int poolb = ((N_NODES + 31) / 32 + 7) / 8;  // 196
  k_pool<<<poolb, 192, 0, stream>>>(P, stats + 3 * 192, gamma + 3 * 96, beta + 3 * 96,
                                    batch, pool);
  k_out<<<(N_GRAPHS * 96 + 255) / 256, 256, 0, stream>>>(pool, gcnt, out);
}

// Round 10
// 602.699 us; speedup vs baseline: 1.7456x; 1.0802x over previous
//
#include <hip/hip_runtime.h>
#include <hip/hip_bf16.h>
#include <hip/hip_fp16.h>

#define N_NODES 50000
#define N_EDGES 800000
#define DD 96
#define NLAYER 4
#define N_GRAPHS 256
#define BN_EPS 1e-5f
#define SLABS 8
#define SFEAT 12        // halfs per slab row (24 B); SLABS*SFEAT = 96
#define NCHUNK 64       // edge chunks (phist/fill blocks)
#define CHUNK_E (N_EDGES / NCHUNK)   // 12500
#define NRANGE 4
#define RANGE_N 12544   // 4*12544 = 50176 >= N_NODES; 50.2 KB LDS hist

// ---------------- workspace layout (units: 4-byte elements) ----------------
enum : size_t {
  O_CNT    = 0,                        // int[N_NODES]
  O_STATS  = O_CNT + N_NODES,          // float[4*192]
  O_POOL   = O_STATS + 4 * 192,        // float[N_GRAPHS*96]
  O_GCNT   = O_POOL + N_GRAPHS * DD,   // int[N_GRAPHS]
  ZERO_END = O_GCNT + N_GRAPHS,        // memset covers stats..gcnt (see launch)
  O_ROWPTR = ZERO_END,                 // int[N_NODES+1]
  O_DIS    = O_ROWPTR + N_NODES + 1,   // float[N_NODES]
  O_BSUMS  = O_DIS + N_NODES,          // int[256]
  O_EDGE   = (O_BSUMS + 256 + 3) & ~size_t(3),        // uint[N_EDGES]
  O_HWH    = (O_EDGE + N_EDGES + 3) & ~size_t(3),     // half[8][50000][12] = 9.6MB
  O_PART   = O_HWH + (size_t)SLABS * N_NODES * SFEAT / 2, // ushort[64][50000] = 6.4MB
  O_LOCC   = O_PART + (size_t)NCHUNK * N_NODES / 2,   // ushort[N_EDGES] = 1.6MB
  O_P      = O_LOCC + N_EDGES / 2,                    // float[N*96] agg
  WS_ELEMS = O_P + (size_t)N_NODES * DD               // ~40.7 MB (ws >= 45 MB ok)
};

__device__ __forceinline__ void atomAddF(float* p, float v) {
  unsafeAtomicAdd(p, v);  // native global fp32 atomic
}

__device__ __forceinline__ float2 h2f(unsigned int u) {
  __half2 h = *(__half2*)&u;
  return __half22float2(h);
}

// ---------------- CSR build, atomic-free ----------------
// Per-chunk LDS histograms; LDS atomicAdd's return value = edge's local
// occurrence index. No global atomics anywhere in the build.
__global__ __launch_bounds__(256) void k_phist(const int* __restrict__ dst,
                                               unsigned short* __restrict__ part,
                                               unsigned short* __restrict__ locc) {
  __shared__ int hist[RANGE_N];
  const int b = blockIdx.x;           // chunk id
  const int tid = threadIdx.x;
  const int e0 = b * CHUNK_E, e1 = e0 + CHUNK_E;
  for (int r = 0; r < NRANGE; ++r) {
    const int r0 = r * RANGE_N;
    for (int i = tid; i < RANGE_N; i += 256) hist[i] = 0;
    __syncthreads();
    for (int e = e0 + tid; e < e1; e += 256) {
      unsigned rel = (unsigned)(dst[e] - r0);
      if (rel < RANGE_N) locc[e] = (unsigned short)atomicAdd(&hist[rel], 1);
    }
    __syncthreads();
    for (int i = tid; i < RANGE_N; i += 256) {
      int n = r0 + i;
      if (n < N_NODES) part[(size_t)b * N_NODES + n] = (unsigned short)hist[i];
    }
    __syncthreads();
  }
}

// per node: scan 64 block-partials -> exclusive offsets (in place), total cnt,
// dis = rsqrt(deg+1), and per-256-node block sums for the rowptr scan.
__global__ __launch_bounds__(256) void k_reduce(unsigned short* __restrict__ part,
                                                int* __restrict__ cnt,
                                                float* __restrict__ dis,
                                                int* __restrict__ bsums) {
  __shared__ int s[256];
  const int tid = threadIdx.x;
  const int n = blockIdx.x * 256 + tid;
  int run = 0;
  if (n < N_NODES) {
#pragma unroll 8
    for (int b = 0; b < NCHUNK; ++b) {
      size_t idx = (size_t)b * N_NODES + n;
      int t = part[idx];
      part[idx] = (unsigned short)run;
      run += t;
    }
    cnt[n] = run;
    dis[n] = rsqrtf((float)(run + 1));  // +1 self loop
  }
  s[tid] = (n < N_NODES) ? run : 0;
  __syncthreads();
  for (int off = 128; off > 0; off >>= 1) {
    if (tid < off) s[tid] += s[tid + off];
    __syncthreads();
  }
  if (tid == 0) bsums[blockIdx.x] = s[0];
}

__device__ __forceinline__ int lbound(const int* __restrict__ a, int v) {
  int lo = 0, hi = N_NODES;
  while (lo < hi) { int m = (lo + hi) >> 1; if (a[m] < v) lo = m + 1; else hi = m; }
  return lo;
}

// exclusive scan of bsums (one block) + gcnt via binary search on sorted batch
__global__ __launch_bounds__(256) void k_scan_bsums(int* __restrict__ bsums, int nb,
                                                    int* __restrict__ rowptr,
                                                    const int* __restrict__ batch,
                                                    int* __restrict__ gcnt) {
  __shared__ int s[256];
  int tid = threadIdx.x;
  int v = (tid < nb) ? bsums[tid] : 0;
  s[tid] = v;
  __syncthreads();
  for (int off = 1; off < 256; off <<= 1) {
    int add = (tid >= off) ? s[tid - off] : 0;
    __syncthreads();
    s[tid] += add;
    __syncthreads();
  }
  if (tid < nb) bsums[tid] = s[tid] - v;  // exclusive
  if (tid == 255) rowptr[N_NODES] = s[255];
  // per-graph node counts (batch sorted): gcnt[g] = lb(g+1) - lb(g)
  gcnt[tid] = lbound(batch, tid + 1) - lbound(batch, tid);
}

// block-local exclusive scan + global offset -> rowptr
__global__ __launch_bounds__(256) void k_scan_write(const int* __restrict__ cnt,
                                                    const int* __restrict__ bsums,
                                                    int* __restrict__ rowptr) {
  __shared__ int s[256];
  int i = blockIdx.x * 256 + threadIdx.x;
  int v = (i < N_NODES) ? cnt[i] : 0;
  s[threadIdx.x] = v;
  __syncthreads();
  for (int off = 1; off < 256; off <<= 1) {
    int x = 0;
    if (threadIdx.x >= off) x = s[threadIdx.x - off];
    __syncthreads();
    s[threadIdx.x] += x;
    __syncthreads();
  }
  if (i < N_NODES) rowptr[i] = bsums[blockIdx.x] + s[threadIdx.x] - v;  // exclusive
}

// atomic-free fill: pos = rowptr[d] + part[chunk][d] + locc[e]
__global__ __launch_bounds__(256) void k_fill(const int* __restrict__ ei,
                                              const int* __restrict__ rowptr,
                                              const unsigned short* __restrict__ part,
                                              const unsigned short* __restrict__ locc,
                                              const float* __restrict__ dis,
                                              unsigned int* __restrict__ edg) {
  int e = blockIdx.x * 256 + threadIdx.x;
  if (e >= N_EDGES) return;
  int s = ei[e];            // src (< 65536)
  int d = ei[N_EDGES + e];  // dst
  int chunk = e / CHUNK_E;
  int pos = rowptr[d] + (int)part[(size_t)chunk * N_NODES + d] + (int)locc[e];
  unsigned short wb = __half_as_ushort(__float2half_rn(dis[s] * dis[d]));
  edg[pos] = (unsigned int)s | ((unsigned int)wb << 16);
}

// ---------------- GEMM: Y(fp16 slab-major) = act(X) @ W  (R5 proven) ----------
__global__ __launch_bounds__(192) void k_gemm(const float* __restrict__ X,
                                              const float* __restrict__ Wg,
                                              const float* __restrict__ stats,
                                              const float* __restrict__ gamma,
                                              const float* __restrict__ beta,
                                              __half* __restrict__ Y) {
  __shared__ float Ws[96 * 96];
  __shared__ float Hs[48][100];
  __shared__ float sA[96], sC[96];
  const int tid = threadIdx.x;
  const int fg = tid % 24;
  const int rg = tid / 24;
  const int row0 = blockIdx.x * 48;

  for (int i = tid; i < 96 * 24; i += 192)
    *(float4*)&Ws[i * 4] = *(const float4*)&Wg[i * 4];
  if (tid < 96) {
    if (stats) {
      float mu = stats[tid] * (1.f / N_NODES);
      float var = fmaxf(stats[96 + tid] * (1.f / N_NODES) - mu * mu, 0.f);
      float a = gamma[tid] * rsqrtf(var + BN_EPS);
      sA[tid] = a;
      sC[tid] = beta[tid] - mu * a;
    } else {
      sA[tid] = 1.f;
      sC[tid] = 0.f;
    }
  }
  __syncthreads();
  const bool bn = (stats != nullptr);
  for (int i = tid; i < 48 * 24; i += 192) {
    int r = i / 24, c4 = (i % 24) * 4;
    int gr = row0 + r;
    float4 v = (gr < N_NODES) ? *(const float4*)&X[(size_t)gr * 96 + c4]
                              : make_float4(0.f, 0.f, 0.f, 0.f);
    if (bn) {
      v.x = fmaxf(v.x * sA[c4] + sC[c4], 0.f);
      v.y = fmaxf(v.y * sA[c4 + 1] + sC[c4 + 1], 0.f);
      v.z = fmaxf(v.z * sA[c4 + 2] + sC[c4 + 2], 0.f);
      v.w = fmaxf(v.w * sA[c4 + 3] + sC[c4 + 3], 0.f);
    }
    *(float4*)&Hs[r][c4] = v;
  }
  __syncthreads();

  float4 acc[6];
#pragma unroll
  for (int j = 0; j < 6; ++j) acc[j] = make_float4(0.f, 0.f, 0.f, 0.f);
  const int f4 = fg * 4;
  for (int k4 = 0; k4 < 96; k4 += 4) {
    float4 w0 = *(const float4*)&Ws[(k4 + 0) * 96 + f4];
    float4 w1 = *(const float4*)&Ws[(k4 + 1) * 96 + f4];
    float4 w2 = *(const float4*)&Ws[(k4 + 2) * 96 + f4];
    float4 w3 = *(const float4*)&Ws[(k4 + 3) * 96 + f4];
#pragma unroll
    for (int j = 0; j < 6; ++j) {
      const float4 h = *(const float4*)&Hs[rg + j * 8][k4];
      acc[j].x += h.x * w0.x + h.y * w1.x + h.z * w2.x + h.w * w3.x;
      acc[j].y += h.x * w0.y + h.y * w1.y + h.z * w2.y + h.w * w3.y;
      acc[j].z += h.x * w0.z + h.y * w1.z + h.z * w2.z + h.w * w3.z;
      acc[j].w += h.x * w0.w + h.y * w1.w + h.z * w2.w + h.w * w3.w;
    }
  }
  // write fp16 slab-major: slab = fg/3, offset (fg%3)*4 halfs within 12-half row
  const int slab = fg / 3;
  const int off = (fg % 3) * 4;
#pragma unroll
  for (int j = 0; j < 6; ++j) {
    int r = row0 + rg + j * 8;
    if (r < N_NODES) {
      union { uint2 u; __half2 h[2]; } pk;
      pk.h[0] = __floats2half2_rn(acc[j].x, acc[j].y);
      pk.h[1] = __floats2half2_rn(acc[j].z, acc[j].w);
      *(uint2*)&Y[((size_t)slab * N_NODES + r) * SFEAT + off] = pk.u;
    }
  }
}

// ---------------- fused aggregation + BN-stats (R5 champion config) ----------
__global__ __launch_bounds__(256) void k_gather(const __half* __restrict__ hwh,
                                                const int* __restrict__ rowptr,
                                                const unsigned int* __restrict__ edg,
                                                const float* __restrict__ dis,
                                                float* __restrict__ agg,
                                                float* __restrict__ stats) {
  __shared__ float sred[24];
  const int tid = threadIdx.x;
  const int slab = blockIdx.x & (SLABS - 1);
  const int chunk = blockIdx.x >> 3;
  const int wave = tid >> 6;
  const int lane = tid & 63;
  const int g = lane / 6;      // 0..10 (g==10 -> idle)
  const int ch = lane - g * 6; // channel pair index 0..5
  const int n = chunk * 40 + wave * 10 + g;
  const bool valid = (g < 10) && (n < N_NODES);
  const int nc = valid ? n : 0;

  const unsigned int* slabU =
      (const unsigned int*)(hwh) + (size_t)slab * N_NODES * (SFEAT / 2);

  if (tid < 24) sred[tid] = 0.f;

  const int js = valid ? rowptr[nc] : 0;
  const int je = valid ? rowptr[nc + 1] : 0;

  float a0 = 0.f, a1 = 0.f;
  if (valid) {
    float dn = dis[nc];
    float s2 = dn * dn;  // self-loop weight
    float2 f = h2f(slabU[nc * 6 + ch]);
    a0 = f.x * s2;
    a1 = f.y * s2;
  }

  for (int j = js; j < je; j += 8) {
    unsigned int ew[8];
    unsigned int rv[8];
#pragma unroll
    for (int k = 0; k < 8; ++k) {
      int jk = j + k;
      int jc = jk < je ? jk : (je - 1);  // clamp to hot line
      ew[k] = edg[jc];
    }
#pragma unroll
    for (int k = 0; k < 8; ++k)
      rv[k] = slabU[(int)(ew[k] & 0xFFFFu) * 6 + ch];
#pragma unroll
    for (int k = 0; k < 8; ++k) {
      float w = (j + k < je)
                    ? __half2float(__ushort_as_half((unsigned short)(ew[k] >> 16)))
                    : 0.f;
      float2 f = h2f(rv[k]);
      a0 = fmaf(w, f.x, a0);
      a1 = fmaf(w, f.y, a1);
    }
  }

  if (valid) {
    *(float2*)&agg[(size_t)n * DD + slab * SFEAT + ch * 2] = make_float2(a0, a1);
  }

  __syncthreads();
  if (valid) {
    atomicAdd(&sred[ch * 2], a0);          // LDS ds_add_f32
    atomicAdd(&sred[ch * 2 + 1], a1);
    atomicAdd(&sred[12 + ch * 2], a0 * a0);
    atomicAdd(&sred[13 + ch * 2], a1 * a1);
  }
  __syncthreads();
  if (tid < 24) {
    int c = (tid < 12) ? (slab * SFEAT + tid) : (96 + slab * SFEAT + tid - 12);
    atomAddF(&stats[c], sred[tid]);
  }
}

// ---------------- pooling: final BN+ReLU + segment-sum over sorted batch ------
__global__ __launch_bounds__(192) void k_pool(const float* __restrict__ h,
                                              const float* __restrict__ stats,
                                              const float* __restrict__ gamma,
                                              const float* __restrict__ beta,
                                              const int* __restrict__ batch,
                                              float* __restrict__ pool) {
  __shared__ float sA[96], sC[96];
  const int tid = threadIdx.x;
  if (tid < 96) {
    float mu = stats[tid] * (1.f / N_NODES);
    float var = fmaxf(stats[96 + tid] * (1.f / N_NODES) - mu * mu, 0.f);
    float a = gamma[tid] * rsqrtf(var + BN_EPS);
    sA[tid] = a;
    sC[tid] = beta[tid] - mu * a;
  }
  __syncthreads();
  const int chain = blockIdx.x * 8 + tid / 24;
  const int q4 = (tid % 24) * 4;
  int n0 = chain * 32;
  if (n0 >= N_NODES) return;
  int n1 = min(n0 + 32, N_NODES);
  float A0 = sA[q4], A1 = sA[q4 + 1], A2 = sA[q4 + 2], A3 = sA[q4 + 3];
  float C0 = sC[q4], C1 = sC[q4 + 1], C2 = sC[q4 + 2], C3 = sC[q4 + 3];
  int cur = batch[n0];
  float4 acc = make_float4(0.f, 0.f, 0.f, 0.f);
  for (int n = n0; n < n1; ++n) {
    int g = batch[n];
    if (g != cur) {
      float* p = &pool[cur * 96 + q4];
      atomAddF(p, acc.x); atomAddF(p + 1, acc.y);
      atomAddF(p + 2, acc.z); atomAddF(p + 3, acc.w);
      acc = make_float4(0.f, 0.f, 0.f, 0.f);
      cur = g;
    }
    const float4 v = *(const float4*)&h[(size_t)n * 96 + q4];
    acc.x += fmaxf(v.x * A0 + C0, 0.f);
    acc.y += fmaxf(v.y * A1 + C1, 0.f);
    acc.z += fmaxf(v.z * A2 + C2, 0.f);
    acc.w += fmaxf(v.w * A3 + C3, 0.f);
  }
  float* p = &pool[cur * 96 + q4];
  atomAddF(p, acc.x); atomAddF(p + 1, acc.y);
  atomAddF(p + 2, acc.z); atomAddF(p + 3, acc.w);
}

__global__ void k_out(const float* __restrict__ pool, const int* __restrict__ gcnt,
                      float* __restrict__ out) {
  int t = blockIdx.x * blockDim.x + threadIdx.x;
  if (t >= N_GRAPHS * 96) return;
  int g = t / 96;
  int c = gcnt[g];
  if (c < 1) c = 1;
  out[t] = pool[t] / (float)c;
}

extern "C" void kernel_launch(void* const* d_in, const int* in_sizes, int n_in,
                              void* d_out, int out_size, void* d_ws, size_t ws_size,
                              hipStream_t stream) {
  const float* x     = (const float*)d_in[0];
  const int*   ei    = (const int*)d_in[1];   // [2, E]: src row then dst row
  const int*   batch = (const int*)d_in[2];
  const float* W     = (const float*)d_in[3]; // [4,96,96]
  // d_in[4] = b : cancels exactly through BatchNorm, unused
  const float* gamma = (const float*)d_in[5]; // [4,96]
  const float* beta  = (const float*)d_in[6];
  float* out = (float*)d_out;

  float* ws = (float*)d_ws;
  int*   cnt    = (int*)(ws + O_CNT);
  float* stats  = ws + O_STATS;
  float* pool   = ws + O_POOL;
  int*   gcnt   = (int*)(ws + O_GCNT);
  int*   rowptr = (int*)(ws + O_ROWPTR);
  float* dis    = ws + O_DIS;
  int*   bsums  = (int*)(ws + O_BSUMS);
  unsigned int* edg = (unsigned int*)(ws + O_EDGE);
  __half* hwh   = (__half*)(ws + O_HWH);
  unsigned short* part = (unsigned short*)(ws + O_PART);
  unsigned short* locc = (unsigned short*)(ws + O_LOCC);
  float* P      = ws + O_P;  // agg (fp32)

  // zero only stats + pool (atomically accumulated); everything else is written
  hipMemsetAsync(stats, 0, (ZERO_END - O_STATS) * sizeof(float), stream);

  const int eb = (N_EDGES + 255) / 256;
  const int nb = (N_NODES + 255) / 256;  // 196
  k_phist<<<NCHUNK, 256, 0, stream>>>(ei + N_EDGES, part, locc);
  k_reduce<<<nb, 256, 0, stream>>>(part, cnt, dis, bsums);
  k_scan_bsums<<<1, 256, 0, stream>>>(bsums, nb, rowptr, batch, gcnt);
  k_scan_write<<<nb, 256, 0, stream>>>(cnt, bsums, rowptr);
  k_fill<<<eb, 256, 0, stream>>>(ei, rowptr, part, locc, dis, edg);

  const int gemmb = (N_NODES + 47) / 48;              // 1042
  const int gatherb = SLABS * ((N_NODES + 39) / 40);  // 10000

  const float* hin = x;
  for (int l = 0; l < NLAYER; ++l) {
    const float* st = (l == 0) ? nullptr : (stats + (l - 1) * 192);
    const float* ga = (l == 0) ? nullptr : (gamma + (l - 1) * 96);
    const float* be = (l == 0) ? nullptr : (beta + (l - 1) * 96);
    k_gemm<<<gemmb, 192, 0, stream>>>(hin, W + l * 96 * 96, st, ga, be, hwh);
    k_gather<<<gatherb, 256, 0, stream>>>(hwh, rowptr, edg, dis, P, stats + l * 192);
    hin = P;
  }

  const int poolb = ((N_NODES + 31) / 32 + 7) / 8;  // 196
  k_pool<<<poolb, 192, 0, stream>>>(P, stats + 3 * 192, gamma + 3 * 96, beta + 3 * 96,
                                    batch, pool);
  k_out<<<(N_GRAPHS * 96 + 255) / 256, 256, 0, stream>>>(pool, gcnt, out);
}

// Round 11
// 576.089 us; speedup vs baseline: 1.8262x; 1.0462x over previous
//
#include <hip/hip_runtime.h>
#include <hip/hip_bf16.h>
#include <hip/hip_fp16.h>

#define N_NODES 50000
#define N_EDGES 800000
#define DD 96
#define NLAYER 4
#define N_GRAPHS 256
#define BN_EPS 1e-5f
#define SLABS 8
#define SFEAT 12        // used halfs per slab row
#define GSU 8           // uints per slab row (32 B, exactly one cache line)
#define NCHUNK 64
#define CHUNK_E (N_EDGES / NCHUNK)   // 12500
#define NRANGE 4
#define RANGE_N 12544

typedef _Float16 half8_t __attribute__((ext_vector_type(8)));
typedef float floatx4 __attribute__((ext_vector_type(4)));

// ---------------- workspace layout (units: 4-byte elements) ----------------
enum : size_t {
  O_CNT    = 0,                        // int[N_NODES]
  O_STATS  = O_CNT + N_NODES,          // float[4*192]
  O_POOL   = O_STATS + 4 * 192,        // float[N_GRAPHS*96]
  O_GCNT   = O_POOL + N_GRAPHS * DD,   // int[N_GRAPHS]
  ZERO_END = O_GCNT + N_GRAPHS,
  O_ROWPTR = ZERO_END,                 // int[N_NODES+1]
  O_DIS    = O_ROWPTR + N_NODES + 1,   // float[N_NODES]
  O_BSUMS  = O_DIS + N_NODES,          // int[256]
  O_EDGE   = (O_BSUMS + 256 + 7) & ~size_t(7),        // uint[N_EDGES]
  O_HWH    = (O_EDGE + N_EDGES + 7) & ~size_t(7),     // uint[8][50000][8] = 12.8MB (32B rows)
  O_PART   = O_HWH + (size_t)SLABS * N_NODES * GSU,   // ushort[64][50000]
  O_LOCC   = O_PART + (size_t)NCHUNK * N_NODES / 2,   // ushort[N_EDGES]
  O_P      = O_LOCC + N_EDGES / 2,                    // float[N*96] agg
  WS_ELEMS = O_P + (size_t)N_NODES * DD
};

__device__ __forceinline__ void atomAddF(float* p, float v) {
  unsafeAtomicAdd(p, v);
}

__device__ __forceinline__ float2 h2f(unsigned int u) {
  __half2 h = *(__half2*)&u;
  return __half22float2(h);
}

// ---------------- CSR build, atomic-free (R10 proven) ----------------
__global__ __launch_bounds__(256) void k_phist(const int* __restrict__ dst,
                                               unsigned short* __restrict__ part,
                                               unsigned short* __restrict__ locc) {
  __shared__ int hist[RANGE_N];
  const int b = blockIdx.x;
  const int tid = threadIdx.x;
  const int e0 = b * CHUNK_E, e1 = e0 + CHUNK_E;
  for (int r = 0; r < NRANGE; ++r) {
    const int r0 = r * RANGE_N;
    for (int i = tid; i < RANGE_N; i += 256) hist[i] = 0;
    __syncthreads();
    for (int e = e0 + tid; e < e1; e += 256) {
      unsigned rel = (unsigned)(dst[e] - r0);
      if (rel < RANGE_N) locc[e] = (unsigned short)atomicAdd(&hist[rel], 1);
    }
    __syncthreads();
    for (int i = tid; i < RANGE_N; i += 256) {
      int n = r0 + i;
      if (n < N_NODES) part[(size_t)b * N_NODES + n] = (unsigned short)hist[i];
    }
    __syncthreads();
  }
}

__global__ __launch_bounds__(256) void k_reduce(unsigned short* __restrict__ part,
                                                int* __restrict__ cnt,
                                                float* __restrict__ dis,
                                                int* __restrict__ bsums) {
  __shared__ int s[256];
  const int tid = threadIdx.x;
  const int n = blockIdx.x * 256 + tid;
  int run = 0;
  if (n < N_NODES) {
#pragma unroll 8
    for (int b = 0; b < NCHUNK; ++b) {
      size_t idx = (size_t)b * N_NODES + n;
      int t = part[idx];
      part[idx] = (unsigned short)run;
      run += t;
    }
    cnt[n] = run;
    dis[n] = rsqrtf((float)(run + 1));
  }
  s[tid] = (n < N_NODES) ? run : 0;
  __syncthreads();
  for (int off = 128; off > 0; off >>= 1) {
    if (tid < off) s[tid] += s[tid + off];
    __syncthreads();
  }
  if (tid == 0) bsums[blockIdx.x] = s[0];
}

__device__ __forceinline__ int lbound(const int* __restrict__ a, int v) {
  int lo = 0, hi = N_NODES;
  while (lo < hi) { int m = (lo + hi) >> 1; if (a[m] < v) lo = m + 1; else hi = m; }
  return lo;
}

__global__ __launch_bounds__(256) void k_scan_bsums(int* __restrict__ bsums, int nb,
                                                    int* __restrict__ rowptr,
                                                    const int* __restrict__ batch,
                                                    int* __restrict__ gcnt) {
  __shared__ int s[256];
  int tid = threadIdx.x;
  int v = (tid < nb) ? bsums[tid] : 0;
  s[tid] = v;
  __syncthreads();
  for (int off = 1; off < 256; off <<= 1) {
    int add = (tid >= off) ? s[tid - off] : 0;
    __syncthreads();
    s[tid] += add;
    __syncthreads();
  }
  if (tid < nb) bsums[tid] = s[tid] - v;
  if (tid == 255) rowptr[N_NODES] = s[255];
  gcnt[tid] = lbound(batch, tid + 1) - lbound(batch, tid);
}

__global__ __launch_bounds__(256) void k_scan_write(const int* __restrict__ cnt,
                                                    const int* __restrict__ bsums,
                                                    int* __restrict__ rowptr) {
  __shared__ int s[256];
  int i = blockIdx.x * 256 + threadIdx.x;
  int v = (i < N_NODES) ? cnt[i] : 0;
  s[threadIdx.x] = v;
  __syncthreads();
  for (int off = 1; off < 256; off <<= 1) {
    int x = 0;
    if (threadIdx.x >= off) x = s[threadIdx.x - off];
    __syncthreads();
    s[threadIdx.x] += x;
    __syncthreads();
  }
  if (i < N_NODES) rowptr[i] = bsums[blockIdx.x] + s[threadIdx.x] - v;
}

__global__ __launch_bounds__(256) void k_fill(const int* __restrict__ ei,
                                              const int* __restrict__ rowptr,
                                              const unsigned short* __restrict__ part,
                                              const unsigned short* __restrict__ locc,
                                              const float* __restrict__ dis,
                                              unsigned int* __restrict__ edg) {
  int e = blockIdx.x * 256 + threadIdx.x;
  if (e >= N_EDGES) return;
  int s = ei[e];
  int d = ei[N_EDGES + e];
  int chunk = e / CHUNK_E;
  int pos = rowptr[d] + (int)part[(size_t)chunk * N_NODES + d] + (int)locc[e];
  unsigned short wb = __half_as_ushort(__float2half_rn(dis[s] * dis[d]));
  edg[pos] = (unsigned int)s | ((unsigned int)wb << 16);
}

// ---------------- GEMM via MFMA fp16: Y(slab-major fp16) = act(X) @ W ----------
// 256 thr = 4 waves; block tile M=64, N=96, K=96. Wave w: rows w*16..w*16+16.
// A[m=lane&15][k=quad*8+j] ; B[n=lane&15][k=quad*8+j] (from transposed Wt) ;
// C/D row=quad*4+reg, col=lane&15. fp32 accum.
__global__ __launch_bounds__(256) void k_gemm(const float* __restrict__ X,
                                              const float* __restrict__ Wg,
                                              const float* __restrict__ stats,
                                              const float* __restrict__ gamma,
                                              const float* __restrict__ beta,
                                              unsigned int* __restrict__ Yu) {
  __shared__ _Float16 Xh[64 * 104];   // act tile, row stride 104 halfs (208 B)
  __shared__ _Float16 Wt[96 * 104];   // W transposed: Wt[n][k]
  __shared__ float sA[96], sC[96];
  const int tid = threadIdx.x;
  const int row0 = blockIdx.x * 64;

  if (tid < 96) {
    if (stats) {
      float mu = stats[tid] * (1.f / N_NODES);
      float var = fmaxf(stats[96 + tid] * (1.f / N_NODES) - mu * mu, 0.f);
      float a = gamma[tid] * rsqrtf(var + BN_EPS);
      sA[tid] = a;
      sC[tid] = beta[tid] - mu * a;
    } else {
      sA[tid] = 1.f;
      sC[tid] = 0.f;
    }
  }
  // stage W transposed as fp16 (does not need sA)
  for (int i = tid; i < 96 * 24; i += 256) {
    int n = i / 24, k0 = (i % 24) * 4;
    union { _Float16 h[4]; uint2 u; } pk;
    pk.h[0] = (_Float16)Wg[(k0 + 0) * 96 + n];
    pk.h[1] = (_Float16)Wg[(k0 + 1) * 96 + n];
    pk.h[2] = (_Float16)Wg[(k0 + 2) * 96 + n];
    pk.h[3] = (_Float16)Wg[(k0 + 3) * 96 + n];
    *(uint2*)&Wt[n * 104 + k0] = pk.u;
  }
  __syncthreads();  // sA/sC visible
  const bool bn = (stats != nullptr);
  for (int i = tid; i < 64 * 24; i += 256) {
    int r = i / 24, c4 = (i % 24) * 4;
    int gr = row0 + r;
    float4 v = (gr < N_NODES) ? *(const float4*)&X[(size_t)gr * 96 + c4]
                              : make_float4(0.f, 0.f, 0.f, 0.f);
    if (bn) {
      v.x = fmaxf(v.x * sA[c4] + sC[c4], 0.f);
      v.y = fmaxf(v.y * sA[c4 + 1] + sC[c4 + 1], 0.f);
      v.z = fmaxf(v.z * sA[c4 + 2] + sC[c4 + 2], 0.f);
      v.w = fmaxf(v.w * sA[c4 + 3] + sC[c4 + 3], 0.f);
    }
    union { _Float16 h[4]; uint2 u; } pk;
    pk.h[0] = (_Float16)v.x; pk.h[1] = (_Float16)v.y;
    pk.h[2] = (_Float16)v.z; pk.h[3] = (_Float16)v.w;
    *(uint2*)&Xh[r * 104 + c4] = pk.u;
  }
  __syncthreads();

  const int w = tid >> 6, lane = tid & 63;
  const int quad = lane >> 4, l16 = lane & 15;

  half8_t a[3];
#pragma unroll
  for (int kb = 0; kb < 3; ++kb)
    a[kb] = *(const half8_t*)&Xh[(w * 16 + l16) * 104 + kb * 32 + quad * 8];

  floatx4 acc[6];
#pragma unroll
  for (int nt = 0; nt < 6; ++nt) acc[nt] = (floatx4){0.f, 0.f, 0.f, 0.f};
#pragma unroll
  for (int nt = 0; nt < 6; ++nt) {
#pragma unroll
    for (int kb = 0; kb < 3; ++kb) {
      half8_t b = *(const half8_t*)&Wt[(nt * 16 + l16) * 104 + kb * 32 + quad * 8];
      acc[nt] = __builtin_amdgcn_mfma_f32_16x16x32_f16(a[kb], b, acc[nt], 0, 0, 0);
    }
  }

  __syncthreads();  // done reading Xh/Wt; reuse Xh for C repack
#pragma unroll
  for (int nt = 0; nt < 6; ++nt) {
#pragma unroll
    for (int reg = 0; reg < 4; ++reg) {
      int r = w * 16 + quad * 4 + reg;
      Xh[r * 104 + nt * 16 + l16] = (_Float16)acc[nt][reg];
    }
  }
  __syncthreads();
  // write out slab-major 32B rows: 64 r x 8 slabs x 3 uint2 = 1536 items
  for (int i = tid; i < 64 * 24; i += 256) {
    int r = i / 24, rem = i % 24;
    int slab = rem / 3, up = rem % 3;
    int node = row0 + r;
    if (node < N_NODES) {
      uint2 u = *(const uint2*)&Xh[r * 104 + slab * SFEAT + up * 4];
      *(uint2*)&Yu[((size_t)slab * N_NODES + node) * GSU + up * 2] = u;
    }
  }
}

// ---------------- fused aggregation + BN-stats (R5 structure, 32B rows) -------
__global__ __launch_bounds__(256) void k_gather(const unsigned int* __restrict__ hw4,
                                                const int* __restrict__ rowptr,
                                                const unsigned int* __restrict__ edg,
                                                const float* __restrict__ dis,
                                                float* __restrict__ agg,
                                                float* __restrict__ stats) {
  __shared__ float sred[24];
  const int tid = threadIdx.x;
  const int slab = blockIdx.x & (SLABS - 1);
  const int chunk = blockIdx.x >> 3;
  const int wave = tid >> 6;
  const int lane = tid & 63;
  const int g = lane / 6;      // 0..10 (g==10 -> idle)
  const int ch = lane - g * 6; // uint index 0..5 within 8-uint row
  const int n = chunk * 40 + wave * 10 + g;
  const bool valid = (g < 10) && (n < N_NODES);
  const int nc = valid ? n : 0;

  const unsigned int* slabU = hw4 + (size_t)slab * N_NODES * GSU;

  if (tid < 24) sred[tid] = 0.f;

  const int js = valid ? rowptr[nc] : 0;
  const int je = valid ? rowptr[nc + 1] : 0;

  float a0 = 0.f, a1 = 0.f;
  if (valid) {
    float dn = dis[nc];
    float s2 = dn * dn;  // self-loop weight
    float2 f = h2f(slabU[nc * GSU + ch]);
    a0 = f.x * s2;
    a1 = f.y * s2;
  }

  for (int j = js; j < je; j += 8) {
    unsigned int ew[8];
    unsigned int rv[8];
#pragma unroll
    for (int k = 0; k < 8; ++k) {
      int jk = j + k;
      int jc = jk < je ? jk : (je - 1);  // clamp to hot line
      ew[k] = edg[jc];
    }
#pragma unroll
    for (int k = 0; k < 8; ++k)
      rv[k] = slabU[(size_t)(ew[k] & 0xFFFFu) * GSU + ch];
#pragma unroll
    for (int k = 0; k < 8; ++k) {
      float w = (j + k < je)
                    ? __half2float(__ushort_as_half((unsigned short)(ew[k] >> 16)))
                    : 0.f;
      float2 f = h2f(rv[k]);
      a0 = fmaf(w, f.x, a0);
      a1 = fmaf(w, f.y, a1);
    }
  }

  if (valid) {
    *(float2*)&agg[(size_t)n * DD + slab * SFEAT + ch * 2] = make_float2(a0, a1);
  }

  __syncthreads();
  if (valid) {
    atomicAdd(&sred[ch * 2], a0);
    atomicAdd(&sred[ch * 2 + 1], a1);
    atomicAdd(&sred[12 + ch * 2], a0 * a0);
    atomicAdd(&sred[13 + ch * 2], a1 * a1);
  }
  __syncthreads();
  if (tid < 24) {
    int c = (tid < 12) ? (slab * SFEAT + tid) : (96 + slab * SFEAT + tid - 12);
    atomAddF(&stats[c], sred[tid]);
  }
}

// ---------------- pooling: final BN+ReLU + segment-sum over sorted batch ------
__global__ __launch_bounds__(192) void k_pool(const float* __restrict__ h,
                                              const float* __restrict__ stats,
                                              const float* __restrict__ gamma,
                                              const float* __restrict__ beta,
                                              const int* __restrict__ batch,
                                              float* __restrict__ pool) {
  __shared__ float sA[96], sC[96];
  const int tid = threadIdx.x;
  if (tid < 96) {
    float mu = stats[tid] * (1.f / N_NODES);
    float var = fmaxf(stats[96 + tid] * (1.f / N_NODES) - mu * mu, 0.f);
    float a = gamma[tid] * rsqrtf(var + BN_EPS);
    sA[tid] = a;
    sC[tid] = beta[tid] - mu * a;
  }
  __syncthreads();
  const int chain = blockIdx.x * 8 + tid / 24;
  const int q4 = (tid % 24) * 4;
  int n0 = chain * 32;
  if (n0 >= N_NODES) return;
  int n1 = min(n0 + 32, N_NODES);
  float A0 = sA[q4], A1 = sA[q4 + 1], A2 = sA[q4 + 2], A3 = sA[q4 + 3];
  float C0 = sC[q4], C1 = sC[q4 + 1], C2 = sC[q4 + 2], C3 = sC[q4 + 3];
  int cur = batch[n0];
  float4 acc = make_float4(0.f, 0.f, 0.f, 0.f);
  for (int n = n0; n < n1; ++n) {
    int g = batch[n];
    if (g != cur) {
      float* p = &pool[cur * 96 + q4];
      atomAddF(p, acc.x); atomAddF(p + 1, acc.y);
      atomAddF(p + 2, acc.z); atomAddF(p + 3, acc.w);
      acc = make_float4(0.f, 0.f, 0.f, 0.f);
      cur = g;
    }
    const float4 v = *(const float4*)&h[(size_t)n * 96 + q4];
    acc.x += fmaxf(v.x * A0 + C0, 0.f);
    acc.y += fmaxf(v.y * A1 + C1, 0.f);
    acc.z += fmaxf(v.z * A2 + C2, 0.f);
    acc.w += fmaxf(v.w * A3 + C3, 0.f);
  }
  float* p = &pool[cur * 96 + q4];
  atomAddF(p, acc.x); atomAddF(p + 1, acc.y);
  atomAddF(p + 2, acc.z); atomAddF(p + 3, acc.w);
}

__global__ void k_out(const float* __restrict__ pool, const int* __restrict__ gcnt,
                      float* __restrict__ out) {
  int t = blockIdx.x * blockDim.x + threadIdx.x;
  if (t >= N_GRAPHS * 96) return;
  int g = t / 96;
  int c = gcnt[g];
  if (c < 1) c = 1;
  out[t] = pool[t] / (float)c;
}

extern "C" void kernel_launch(void* const* d_in, const int* in_sizes, int n_in,
                              void* d_out, int out_size, void* d_ws, size_t ws_size,
                              hipStream_t stream) {
  const float* x     = (const float*)d_in[0];
  const int*   ei    = (const int*)d_in[1];
  const int*   batch = (const int*)d_in[2];
  const float* W     = (const float*)d_in[3];
  // d_in[4] = b : cancels exactly through BatchNorm, unused
  const float* gamma = (const float*)d_in[5];
  const float* beta  = (const float*)d_in[6];
  float* out = (float*)d_out;

  float* ws = (float*)d_ws;
  int*   cnt    = (int*)(ws + O_CNT);
  float* stats  = ws + O_STATS;
  float* pool   = ws + O_POOL;
  int*   gcnt   = (int*)(ws + O_GCNT);
  int*   rowptr = (int*)(ws + O_ROWPTR);
  float* dis    = ws + O_DIS;
  int*   bsums  = (int*)(ws + O_BSUMS);
  unsigned int* edg = (unsigned int*)(ws + O_EDGE);
  unsigned int* hw4 = (unsigned int*)(ws + O_HWH);
  unsigned short* part = (unsigned short*)(ws + O_PART);
  unsigned short* locc = (unsigned short*)(ws + O_LOCC);
  float* P      = ws + O_P;

  hipMemsetAsync(stats, 0, (ZERO_END - O_STATS) * sizeof(float), stream);

  const int eb = (N_EDGES + 255) / 256;
  const int nb = (N_NODES + 255) / 256;  // 196
  k_phist<<<NCHUNK, 256, 0, stream>>>(ei + N_EDGES, part, locc);
  k_reduce<<<nb, 256, 0, stream>>>(part, cnt, dis, bsums);
  k_scan_bsums<<<1, 256, 0, stream>>>(bsums, nb, rowptr, batch, gcnt);
  k_scan_write<<<nb, 256, 0, stream>>>(cnt, bsums, rowptr);
  k_fill<<<eb, 256, 0, stream>>>(ei, rowptr, part, locc, dis, edg);

  const int gemmb = (N_NODES + 63) / 64;              // 782
  const int gatherb = SLABS * ((N_NODES + 39) / 40);  // 10000

  const float* hin = x;
  for (int l = 0; l < NLAYER; ++l) {
    const float* st = (l == 0) ? nullptr : (stats + (l - 1) * 192);
    const float* ga = (l == 0) ? nullptr : (gamma + (l - 1) * 96);
    const float* be = (l == 0) ? nullptr : (beta + (l - 1) * 96);
    k_gemm<<<gemmb, 256, 0, stream>>>(hin, W + l * 96 * 96, st, ga, be, hw4);
    k_gather<<<gatherb, 256, 0, stream>>>(hw4, rowptr, edg, dis, P, stats + l * 192);
    hin = P;
  }

  const int poolb = ((N_NODES + 31) / 32 + 7) / 8;  // 196
  k_pool<<<poolb, 192, 0, stream>>>(P, stats + 3 * 192, gamma + 3 * 96, beta + 3 * 96,
                                    batch, pool);
  k_out<<<(N_GRAPHS * 96 + 255) / 256, 256, 0, stream>>>(pool, gcnt, out);
}